// Round 1
// baseline (493.239 us; speedup 1.0000x reference)
//
#include <hip/hip_runtime.h>
#include <math.h>

#define BB 32
#define CCH 128
#define KK 128
#define HWW 192
#define CHUNK 32
#define NKB (KK * BB)   // 4096
#define P2 (2 * HWW)    // 384

// ---------------------------------------------------------------------------
// K1: per (k,b) block computes the 192x192 correlation tile (fp32 vector FMA),
// dual-axis max-pool -> 384 scores (in LDS), then emits 3 scalars:
//   dot_sw[kb] = sum_j score_j * fc_w_j
//   psum[kb]   = sum_j score_j
//   psq[kb]    = sum_j score_j^2
// ---------------------------------------------------------------------------
__global__ __launch_bounds__(256, 2) void corr_kernel(
    const float* __restrict__ feature,
    const float* __restrict__ class_memory,
    const float* __restrict__ fc_w,
    float* __restrict__ dot_sw,
    float* __restrict__ psum,
    float* __restrict__ psq)
{
    __shared__ float Fs[CHUNK][HWW];   // 24 KB
    __shared__ float Ms[CHUNK][HWW];   // 24 KB

    const int kb  = blockIdx.x;
    const int k   = kb >> 5;     // kb / B
    const int b   = kb & 31;     // kb % B
    const int tid = threadIdx.x;
    const int tx  = tid & 15;    // p-tile index
    const int ty  = tid >> 4;    // q-tile index

    float acc[12][12];
#pragma unroll
    for (int i = 0; i < 12; ++i)
#pragma unroll
        for (int j = 0; j < 12; ++j) acc[i][j] = 0.f;

    const float* fbase = feature      + (size_t)b * CCH * HWW;
    const float* mbase = class_memory + (size_t)k * CCH * HWW;

    for (int c0 = 0; c0 < CCH; c0 += CHUNK) {
        __syncthreads();   // protect LDS reuse (prev compute / reduction)
        const float4* fsrc = (const float4*)(fbase + c0 * HWW);
        const float4* msrc = (const float4*)(mbase + c0 * HWW);
        float4* fdst = (float4*)&Fs[0][0];
        float4* mdst = (float4*)&Ms[0][0];
#pragma unroll
        for (int r = 0; r < 6; ++r) {          // 1536 float4 per array / 256 thr
            int idx = tid + 256 * r;
            fdst[idx] = fsrc[idx];
            mdst[idx] = msrc[idx];
        }
        __syncthreads();
        for (int c = 0; c < CHUNK; ++c) {
            float4 a0 = *(const float4*)&Fs[c][ty * 12];
            float4 a1 = *(const float4*)&Fs[c][ty * 12 + 4];
            float4 a2 = *(const float4*)&Fs[c][ty * 12 + 8];
            float4 b0 = *(const float4*)&Ms[c][tx * 12];
            float4 b1 = *(const float4*)&Ms[c][tx * 12 + 4];
            float4 b2 = *(const float4*)&Ms[c][tx * 12 + 8];
            float af[12] = {a0.x,a0.y,a0.z,a0.w, a1.x,a1.y,a1.z,a1.w, a2.x,a2.y,a2.z,a2.w};
            float bm[12] = {b0.x,b0.y,b0.z,b0.w, b1.x,b1.y,b1.z,b1.w, b2.x,b2.y,b2.z,b2.w};
#pragma unroll
            for (int i = 0; i < 12; ++i)
#pragma unroll
                for (int j = 0; j < 12; ++j)
                    acc[i][j] = fmaf(af[i], bm[j], acc[i][j]);
        }
    }

    // Per-thread partial maxima. corr[q][p]: colmax = max over q (score first
    // half, per p), rowmax = max over p (score second half, per q).
    float colmax[12], rowmax[12];
#pragma unroll
    for (int j = 0; j < 12; ++j) { colmax[j] = -INFINITY; rowmax[j] = -INFINITY; }
#pragma unroll
    for (int i = 0; i < 12; ++i)
#pragma unroll
        for (int j = 0; j < 12; ++j) {
            colmax[j] = fmaxf(colmax[j], acc[i][j]);
            rowmax[i] = fmaxf(rowmax[i], acc[i][j]);
        }

    float (*red)[HWW] = (float(*)[HWW])&Fs[0][0];  // [16][192], reuses Fs
    float* scores_s   = &Ms[0][0];                 // [384],     reuses Ms

    __syncthreads();   // all LDS compute reads done
#pragma unroll
    for (int j = 0; j < 12; ++j) red[ty][tx * 12 + j] = colmax[j];
    __syncthreads();
    if (tid < HWW) {
        float v = -INFINITY;
#pragma unroll
        for (int t = 0; t < 16; ++t) v = fmaxf(v, red[t][tid]);
        scores_s[tid] = v;                         // max over q, per p
    }
    __syncthreads();
#pragma unroll
    for (int i = 0; i < 12; ++i) red[tx][ty * 12 + i] = rowmax[i];
    __syncthreads();
    if (tid < HWW) {
        float v = -INFINITY;
#pragma unroll
        for (int t = 0; t < 16; ++t) v = fmaxf(v, red[t][tid]);
        scores_s[HWW + tid] = v;                   // max over p, per q
    }
    __syncthreads();

    // wave 0: dot with fc_w + BN partial sums over the 384 scores
    if (tid < 64) {
        float ds = 0.f, s1 = 0.f, s2 = 0.f;
#pragma unroll
        for (int u = 0; u < 6; ++u) {
            int j = tid + 64 * u;
            float s = scores_s[j];
            float w = fc_w[j];
            ds = fmaf(s, w, ds);
            s1 += s;
            s2 = fmaf(s, s, s2);
        }
        for (int off = 32; off > 0; off >>= 1) {
            ds += __shfl_down(ds, off);
            s1 += __shfl_down(s1, off);
            s2 += __shfl_down(s2, off);
        }
        if (tid == 0) {
            dot_sw[kb] = ds;
            psum[kb]   = s1;
            psq[kb]    = s2;
        }
    }
}

// ---------------------------------------------------------------------------
// K2: single block. BN1 stats from partials -> folded FC -> logits ->
// BN2 -> focal BCE + argmax -> out[0:32]=loss, out[32:64]=acc.
// ---------------------------------------------------------------------------
__device__ __forceinline__ float softplusf(float x) {
    return fmaxf(x, 0.f) + log1pf(expf(-fabsf(x)));
}

__device__ __forceinline__ float block_sum1024(float v, float* tmp) {
    __syncthreads();                         // protect tmp reuse across calls
    for (int off = 32; off > 0; off >>= 1) v += __shfl_down(v, off);
    if ((threadIdx.x & 63) == 0) tmp[threadIdx.x >> 6] = v;
    __syncthreads();
    float r = 0.f;
#pragma unroll
    for (int i = 0; i < 16; ++i) r += tmp[i];  // all threads same order/result
    return r;
}

__global__ __launch_bounds__(1024) void finalize_kernel(
    const float* __restrict__ dot_sw,
    const float* __restrict__ psum,
    const float* __restrict__ psq,
    const float* __restrict__ fc_w,
    const float* __restrict__ fc_b,
    const float* __restrict__ bn_gamma,
    const float* __restrict__ bn_beta,
    const float* __restrict__ logit_gamma,
    const float* __restrict__ logit_beta,
    const int* __restrict__ target,
    float* __restrict__ out)
{
    const int tid = threadIdx.x;
    __shared__ float l_s[NKB];   // 16 KB: normalized logits, [k][b] layout
    __shared__ float tmp[16];

    // ---- BN1 stats over all K*B*384 score elements + sum(fc_w) ----
    float s1 = 0.f, s2 = 0.f, sw = 0.f;
#pragma unroll
    for (int u = 0; u < 4; ++u) {
        int i = tid + 1024 * u;
        s1 += psum[i];
        s2 += psq[i];
    }
    if (tid < P2) sw = fc_w[tid];

    float S1 = block_sum1024(s1, tmp);
    float S2 = block_sum1024(s2, tmp);
    float SW = block_sum1024(sw, tmp);

    const float N1 = (float)NKB * (float)P2;
    float mean1 = S1 / N1;
    float var1  = S2 / N1 - mean1 * mean1;
    float cA = bn_gamma[0] * rsqrtf(var1 + 1e-5f);
    float cB = (bn_beta[0] - cA * mean1) * SW + fc_b[0];

    // ---- raw logits + BN2 stats ----
    float lr[4];
    float t1 = 0.f, t2 = 0.f;
#pragma unroll
    for (int u = 0; u < 4; ++u) {
        int i = tid + 1024 * u;
        lr[u] = fmaf(cA, dot_sw[i], cB);
        t1 += lr[u];
        t2 = fmaf(lr[u], lr[u], t2);
    }
    float T1 = block_sum1024(t1, tmp);
    float T2 = block_sum1024(t2, tmp);
    float mean2 = T1 / (float)NKB;
    float var2  = T2 / (float)NKB - mean2 * mean2;
    float cC = logit_gamma[0] * rsqrtf(var2 + 1e-5f);
    float cD = logit_beta[0] - mean2 * cC;

#pragma unroll
    for (int u = 0; u < 4; ++u) {
        int i = tid + 1024 * u;
        l_s[i] = fmaf(lr[u], cC, cD);
    }
    __syncthreads();

    // ---- focal BCE + argmax: 32 threads per sample b ----
    const int b  = tid >> 5;
    const int tt = tid & 31;
    const int tgt = target[b];
    float loss  = 0.f;
    float bestv = -INFINITY;
    int   bestk = 0x7fffffff;
#pragma unroll
    for (int u = 0; u < 4; ++u) {
        int kk = tt + 32 * u;
        float l = l_s[kk * BB + b];
        float prob = 1.f / (1.f + expf(-l));
        bool pos = (kk == tgt);
        float wgt = pos ? (1.f - prob) : prob;
        float bce = pos ? softplusf(-l) : softplusf(l);
        loss += bce * wgt * wgt;
        if (l > bestv) { bestv = l; bestk = kk; }
        else if (l == bestv && kk < bestk) bestk = kk;
    }
    for (int off = 16; off > 0; off >>= 1) {
        loss += __shfl_down(loss, off, 32);
        float ov = __shfl_down(bestv, off, 32);
        int   ok = __shfl_down(bestk, off, 32);
        if (ov > bestv) { bestv = ov; bestk = ok; }
        else if (ov == bestv && ok < bestk) bestk = ok;
    }
    if (tt == 0) {
        out[b]      = loss;
        out[BB + b] = (bestk == tgt) ? 1.f : 0.f;
    }
}

extern "C" void kernel_launch(void* const* d_in, const int* in_sizes, int n_in,
                              void* d_out, int out_size, void* d_ws, size_t ws_size,
                              hipStream_t stream)
{
    const float* feature      = (const float*)d_in[0];
    const int*   target       = (const int*)d_in[1];
    const float* class_memory = (const float*)d_in[2];
    const float* bn_gamma     = (const float*)d_in[3];
    const float* bn_beta      = (const float*)d_in[4];
    const float* fc_w         = (const float*)d_in[5];
    const float* fc_b         = (const float*)d_in[6];
    const float* logit_gamma  = (const float*)d_in[7];
    const float* logit_beta   = (const float*)d_in[8];
    float* out = (float*)d_out;

    float* wsf    = (float*)d_ws;
    float* dot_sw = wsf;
    float* psum   = wsf + NKB;
    float* psq    = wsf + 2 * NKB;

    corr_kernel<<<NKB, 256, 0, stream>>>(feature, class_memory, fc_w,
                                         dot_sw, psum, psq);
    finalize_kernel<<<1, 1024, 0, stream>>>(dot_sw, psum, psq, fc_w, fc_b,
                                            bn_gamma, bn_beta,
                                            logit_gamma, logit_beta,
                                            target, out);
}

// Round 2
// 249.179 us; speedup vs baseline: 1.9795x; 1.9795x over previous
//
#include <hip/hip_runtime.h>
#include <math.h>

#define BB 32
#define CCH 128
#define KK 128
#define HWW 192
#define NKB (KK * BB)   // 4096
#define P2 (2 * HWW)    // 384

typedef __attribute__((ext_vector_type(8))) __bf16 bf16x8;
typedef __attribute__((ext_vector_type(16))) float f32x16;

// Pack sizes: per entity: 16 ksteps (8 hi + 8 lo) x 6 tiles x 64 lanes x 8 bf16
#define ENT_ELEMS (16 * 6 * 64 * 8)          // 49152 bf16 per entity
#define APACK_ELEMS (BB * ENT_ELEMS)         // 1,572,864
#define BPACK_ELEMS (KK * ENT_ELEMS)         // 6,291,456

// ---------------------------------------------------------------------------
// pack_kernel: fp32 [ent][c][hw] -> bf16 hi/lo MFMA-fragment pack.
// Fragment layout for v_mfma_f32_32x32x16_bf16 operand: lane l holds
// row/col = (l&31), k = (l>>5)*8 + j, j=0..7 contiguous.
// Pack[e][ks2][t][l][j], ks2 = 0..7: hi of channels ks*16.., 8..15: lo.
// ---------------------------------------------------------------------------
__global__ __launch_bounds__(256) void pack_kernel(
    const float* __restrict__ feature,
    const float* __restrict__ class_memory,
    __bf16* __restrict__ A2,
    __bf16* __restrict__ B2)
{
    int gid = blockIdx.x * 256 + threadIdx.x;   // < 160*16*6*64
    int l = gid & 63;
    int r = gid >> 6;
    int t = r % 6;  r /= 6;
    int ks2 = r & 15;
    int e = r >> 4;                              // 0..159: 0..31 = b, 32..159 = k

    int half = ks2 >> 3;                         // 0 = hi, 1 = lo
    int ks   = ks2 & 7;
    int c0 = ks * 16 + (l >> 5) * 8;
    int q  = t * 32 + (l & 31);

    const float* src = (e < BB) ? (feature + (size_t)e * CCH * HWW)
                                : (class_memory + (size_t)(e - BB) * CCH * HWW);
    bf16x8 v;
#pragma unroll
    for (int j = 0; j < 8; ++j) {
        float x = src[(c0 + j) * HWW + q];
        __bf16 h = (__bf16)x;
        v[j] = half ? (__bf16)(x - (float)h) : h;
    }
    __bf16* dst = (e < BB)
        ? (A2 + ((size_t)e * 16 + ks2) * (6 * 512) + t * 512 + l * 8)
        : (B2 + ((size_t)(e - BB) * 16 + ks2) * (6 * 512) + t * 512 + l * 8);
    *(bf16x8*)dst = v;
}

// ---------------------------------------------------------------------------
// corr_mfma: per (k,b) block, 192x192x128 GEMM via bf16x3 MFMA emulation,
// dual-axis max-pool, emit dot_sw/psum/psq.
// 4 waves = 2x2, each 96x96 = 3x3 tiles of 32x32.
// ---------------------------------------------------------------------------
__global__ __launch_bounds__(256, 1) void corr_mfma(
    const __bf16* __restrict__ A2,
    const __bf16* __restrict__ B2,
    const float* __restrict__ fc_w,
    float* __restrict__ dot_sw,
    float* __restrict__ psum,
    float* __restrict__ psq)
{
    // [buf][stream: 0=Ah 1=Al 2=Bh 3=Bl][tile][lane][8]
    __shared__ __bf16 lds[2][4][6][64][8];      // 48 KB

    const int tid = threadIdx.x;
    const int l   = tid & 63;
    const int w   = tid >> 6;
    const int wy  = w >> 1;      // M half
    const int wx  = w & 1;       // N half
    const int hi  = l >> 5;

    const int bid = blockIdx.x;
    const int kb  = (bid & 7) * 512 + (bid >> 3);   // XCD-contiguous k ranges
    const int k   = kb >> 5;
    const int b   = kb & 31;

    const __bf16* Abase = A2 + (size_t)b * ENT_ELEMS;
    const __bf16* Bbase = B2 + (size_t)k * ENT_ELEMS;

    f32x16 acc[3][3];
#pragma unroll
    for (int i = 0; i < 3; ++i)
#pragma unroll
        for (int j = 0; j < 3; ++j)
#pragma unroll
            for (int rr = 0; rr < 16; ++rr) acc[i][j][rr] = 0.f;

    // wave w stages stream w (6 KB = 6 x 1KB chunks)
    const __bf16* sbase = (w == 0) ? Abase : (w == 1) ? (Abase + 8 * 6 * 512)
                        : (w == 2) ? Bbase : (Bbase + 8 * 6 * 512);

    auto do_stage = [&](int buf, int g) {
        const char* gsrc = (const char*)(sbase + g * 6 * 512) + l * 16;
#pragma unroll
        for (int t = 0; t < 6; ++t) {
            __builtin_amdgcn_global_load_lds(
                (const __attribute__((address_space(1))) void*)(gsrc + t * 1024),
                (__attribute__((address_space(3))) void*)(&lds[buf][w][t][0][0]),
                16, 0, 0);
        }
    };

    auto do_compute = [&](int buf) {
        bf16x8 ah[3], al[3], bh[3], bl[3];
#pragma unroll
        for (int i = 0; i < 3; ++i) {
            ah[i] = *(const bf16x8*)&lds[buf][0][wy * 3 + i][l][0];
            al[i] = *(const bf16x8*)&lds[buf][1][wy * 3 + i][l][0];
        }
#pragma unroll
        for (int j = 0; j < 3; ++j) {
            bh[j] = *(const bf16x8*)&lds[buf][2][wx * 3 + j][l][0];
            bl[j] = *(const bf16x8*)&lds[buf][3][wx * 3 + j][l][0];
        }
#pragma unroll
        for (int i = 0; i < 3; ++i)
#pragma unroll
            for (int j = 0; j < 3; ++j) {
                acc[i][j] = __builtin_amdgcn_mfma_f32_32x32x16_bf16(ah[i], bh[j], acc[i][j], 0, 0, 0);
                acc[i][j] = __builtin_amdgcn_mfma_f32_32x32x16_bf16(ah[i], bl[j], acc[i][j], 0, 0, 0);
                acc[i][j] = __builtin_amdgcn_mfma_f32_32x32x16_bf16(al[i], bh[j], acc[i][j], 0, 0, 0);
            }
    };

    do_stage(0, 0);
    __syncthreads();
    int buf = 0;
#pragma unroll
    for (int g = 0; g < 8; ++g) {
        if (g < 7) do_stage(buf ^ 1, g + 1);
        do_compute(buf);
        __syncthreads();
        buf ^= 1;
    }

    // ---- dual-axis max pool ----
    // C/D layout: col = l&31, row = (r&3) + 8*(r>>2) + 4*hi  (verified m74/m101)
    float cm[3];
#pragma unroll
    for (int j = 0; j < 3; ++j) {
        float m = -INFINITY;
#pragma unroll
        for (int i = 0; i < 3; ++i)
#pragma unroll
            for (int rr = 0; rr < 16; ++rr) m = fmaxf(m, acc[i][j][rr]);
        cm[j] = m;
    }
    float rm[48];
#pragma unroll
    for (int i = 0; i < 3; ++i)
#pragma unroll
        for (int rr = 0; rr < 16; ++rr)
            rm[i * 16 + rr] = fmaxf(fmaxf(acc[i][0][rr], acc[i][1][rr]), acc[i][2][rr]);
    // reduce rowmax across the 32 lanes sharing a row set
#pragma unroll
    for (int m = 1; m < 32; m <<= 1)
#pragma unroll
        for (int v = 0; v < 48; ++v) rm[v] = fmaxf(rm[v], __shfl_xor(rm[v], m));

    float* redf   = (float*)&lds[0][0][0][0][0];
    float* colred = redf;          // [4][192]
    float* rowred = redf + 768;    // [2][192]
    float* scores = redf + 1152;   // [384]

    // last compute's LDS reads all completed before the loop's final barrier
#pragma unroll
    for (int j = 0; j < 3; ++j)
        colred[(wy * 2 + hi) * 192 + wx * 96 + j * 32 + (l & 31)] = cm[j];
    if ((l & 31) == 0) {
#pragma unroll
        for (int i = 0; i < 3; ++i)
#pragma unroll
            for (int rr = 0; rr < 16; ++rr) {
                int q = wy * 96 + i * 32 + (rr & 3) + 8 * (rr >> 2) + 4 * hi;
                rowred[wx * 192 + q] = rm[i * 16 + rr];
            }
    }
    __syncthreads();
    if (tid < HWW) {
        float v = fmaxf(fmaxf(colred[tid], colred[192 + tid]),
                        fmaxf(colred[384 + tid], colred[576 + tid]));
        scores[tid] = v;                          // max over q, per p
        scores[HWW + tid] = fmaxf(rowred[tid], rowred[192 + tid]);  // max over p, per q
    }
    __syncthreads();

    if (tid < 64) {
        float ds = 0.f, s1 = 0.f, s2 = 0.f;
#pragma unroll
        for (int u = 0; u < 6; ++u) {
            int j = tid + 64 * u;
            float s = scores[j];
            float ww = fc_w[j];
            ds = fmaf(s, ww, ds);
            s1 += s;
            s2 = fmaf(s, s, s2);
        }
        for (int off = 32; off > 0; off >>= 1) {
            ds += __shfl_down(ds, off);
            s1 += __shfl_down(s1, off);
            s2 += __shfl_down(s2, off);
        }
        if (tid == 0) { dot_sw[kb] = ds; psum[kb] = s1; psq[kb] = s2; }
    }
}

// ---------------------------------------------------------------------------
// finalize: BN1 -> folded FC -> BN2 -> focal BCE + argmax (unchanged from R1)
// ---------------------------------------------------------------------------
__device__ __forceinline__ float softplusf(float x) {
    return fmaxf(x, 0.f) + log1pf(expf(-fabsf(x)));
}

__device__ __forceinline__ float block_sum1024(float v, float* tmp) {
    __syncthreads();
    for (int off = 32; off > 0; off >>= 1) v += __shfl_down(v, off);
    if ((threadIdx.x & 63) == 0) tmp[threadIdx.x >> 6] = v;
    __syncthreads();
    float r = 0.f;
#pragma unroll
    for (int i = 0; i < 16; ++i) r += tmp[i];
    return r;
}

__global__ __launch_bounds__(1024) void finalize_kernel(
    const float* __restrict__ dot_sw,
    const float* __restrict__ psum,
    const float* __restrict__ psq,
    const float* __restrict__ fc_w,
    const float* __restrict__ fc_b,
    const float* __restrict__ bn_gamma,
    const float* __restrict__ bn_beta,
    const float* __restrict__ logit_gamma,
    const float* __restrict__ logit_beta,
    const int* __restrict__ target,
    float* __restrict__ out)
{
    const int tid = threadIdx.x;
    __shared__ float l_s[NKB];
    __shared__ float tmp[16];

    float s1 = 0.f, s2 = 0.f, sw = 0.f;
#pragma unroll
    for (int u = 0; u < 4; ++u) {
        int i = tid + 1024 * u;
        s1 += psum[i];
        s2 += psq[i];
    }
    if (tid < P2) sw = fc_w[tid];

    float S1 = block_sum1024(s1, tmp);
    float S2 = block_sum1024(s2, tmp);
    float SW = block_sum1024(sw, tmp);

    const float N1 = (float)NKB * (float)P2;
    float mean1 = S1 / N1;
    float var1  = S2 / N1 - mean1 * mean1;
    float cA = bn_gamma[0] * rsqrtf(var1 + 1e-5f);
    float cB = (bn_beta[0] - cA * mean1) * SW + fc_b[0];

    float lr[4];
    float t1 = 0.f, t2 = 0.f;
#pragma unroll
    for (int u = 0; u < 4; ++u) {
        int i = tid + 1024 * u;
        lr[u] = fmaf(cA, dot_sw[i], cB);
        t1 += lr[u];
        t2 = fmaf(lr[u], lr[u], t2);
    }
    float T1 = block_sum1024(t1, tmp);
    float T2 = block_sum1024(t2, tmp);
    float mean2 = T1 / (float)NKB;
    float var2  = T2 / (float)NKB - mean2 * mean2;
    float cC = logit_gamma[0] * rsqrtf(var2 + 1e-5f);
    float cD = logit_beta[0] - mean2 * cC;

#pragma unroll
    for (int u = 0; u < 4; ++u) {
        int i = tid + 1024 * u;
        l_s[i] = fmaf(lr[u], cC, cD);
    }
    __syncthreads();

    const int b  = tid >> 5;
    const int tt = tid & 31;
    const int tgt = target[b];
    float loss  = 0.f;
    float bestv = -INFINITY;
    int   bestk = 0x7fffffff;
#pragma unroll
    for (int u = 0; u < 4; ++u) {
        int kk = tt + 32 * u;
        float lg = l_s[kk * BB + b];
        float prob = 1.f / (1.f + expf(-lg));
        bool pos = (kk == tgt);
        float wgt = pos ? (1.f - prob) : prob;
        float bce = pos ? softplusf(-lg) : softplusf(lg);
        loss += bce * wgt * wgt;
        if (lg > bestv) { bestv = lg; bestk = kk; }
        else if (lg == bestv && kk < bestk) bestk = kk;
    }
    for (int off = 16; off > 0; off >>= 1) {
        loss += __shfl_down(loss, off, 32);
        float ov = __shfl_down(bestv, off, 32);
        int   ok = __shfl_down(bestk, off, 32);
        if (ov > bestv) { bestv = ov; bestk = ok; }
        else if (ov == bestv && ok < bestk) bestk = ok;
    }
    if (tt == 0) {
        out[b]      = loss;
        out[BB + b] = (bestk == tgt) ? 1.f : 0.f;
    }
}

extern "C" void kernel_launch(void* const* d_in, const int* in_sizes, int n_in,
                              void* d_out, int out_size, void* d_ws, size_t ws_size,
                              hipStream_t stream)
{
    const float* feature      = (const float*)d_in[0];
    const int*   target       = (const int*)d_in[1];
    const float* class_memory = (const float*)d_in[2];
    const float* bn_gamma     = (const float*)d_in[3];
    const float* bn_beta      = (const float*)d_in[4];
    const float* fc_w         = (const float*)d_in[5];
    const float* fc_b         = (const float*)d_in[6];
    const float* logit_gamma  = (const float*)d_in[7];
    const float* logit_beta   = (const float*)d_in[8];
    float* out = (float*)d_out;

    __bf16* A2 = (__bf16*)d_ws;
    __bf16* B2 = A2 + APACK_ELEMS;
    float* dot_sw = (float*)(B2 + BPACK_ELEMS);
    float* psum   = dot_sw + NKB;
    float* psq    = psum + NKB;

    pack_kernel<<<3840, 256, 0, stream>>>(feature, class_memory, A2, B2);
    corr_mfma<<<NKB, 256, 0, stream>>>(A2, B2, fc_w, dot_sw, psum, psq);
    finalize_kernel<<<1, 1024, 0, stream>>>(dot_sw, psum, psq, fc_w, fc_b,
                                            bn_gamma, bn_beta,
                                            logit_gamma, logit_beta,
                                            target, out);
}

// Round 3
// 204.497 us; speedup vs baseline: 2.4120x; 1.2185x over previous
//
#include <hip/hip_runtime.h>
#include <math.h>

#define BB 32
#define CCH 128
#define KK 128
#define HWW 192
#define NKB (KK * BB)   // 4096
#define P2 (2 * HWW)    // 384

typedef __attribute__((ext_vector_type(8))) __bf16 bf16x8;
typedef __attribute__((ext_vector_type(16))) float f32x16;

// A pack: feature, hi only:  [b][ks 0..7][tile 0..5][lane][8]
// B pack: memory, hi+lo:     [k][ks2 0..15][tile 0..5][lane][8] (8..15 = lo)
#define A_ELEMS (BB * 8 * 6 * 512)    // 786,432
#define B_ELEMS (KK * 16 * 6 * 512)   // 6,291,456

// ---------------------------------------------------------------------------
// pack: fp32 [ent][c][hw] -> bf16 MFMA-fragment packs.
// Fragment layout (v_mfma_f32_32x32x16_bf16 operand, verified R2):
// lane l holds row/col (l&31), k = (l>>5)*8 + j.
// ---------------------------------------------------------------------------
__global__ __launch_bounds__(256) void pack_kernel(
    const float* __restrict__ feature,
    const float* __restrict__ class_memory,
    __bf16* __restrict__ A2,
    __bf16* __restrict__ B2)
{
    int gid = blockIdx.x * 256 + threadIdx.x;   // 1920*256 = 491,520
    if (gid < 98304) {                          // A: 32*8*6*64
        int l = gid & 63;
        int r = gid >> 6;
        int t = r % 6;  r /= 6;
        int ks = r & 7;
        int e = r >> 3;
        const float* src = feature + (size_t)e * CCH * HWW;
        int c0 = ks * 16 + (l >> 5) * 8;
        int q  = t * 32 + (l & 31);
        bf16x8 v;
#pragma unroll
        for (int j = 0; j < 8; ++j) v[j] = (__bf16)src[(c0 + j) * HWW + q];
        *(bf16x8*)(A2 + ((size_t)(e * 8 + ks) * 6 + t) * 512 + l * 8) = v;
    } else {                                    // B: 128*8*6*64 (hi+lo fused)
        int g2 = gid - 98304;
        int l = g2 & 63;
        int r = g2 >> 6;
        int t = r % 6;  r /= 6;
        int ks = r & 7;
        int e = r >> 3;
        const float* src = class_memory + (size_t)e * CCH * HWW;
        int c0 = ks * 16 + (l >> 5) * 8;
        int q  = t * 32 + (l & 31);
        bf16x8 vh, vl;
#pragma unroll
        for (int j = 0; j < 8; ++j) {
            float x = src[(c0 + j) * HWW + q];
            __bf16 h = (__bf16)x;
            vh[j] = h;
            vl[j] = (__bf16)(x - (float)h);
        }
        __bf16* base = B2 + ((size_t)e * 16 + ks) * 3072 + t * 512 + l * 8;
        *(bf16x8*)base = vh;
        *(bf16x8*)(base + 8 * 3072) = vl;       // lo at ks2 = 8+ks
    }
}

// ---------------------------------------------------------------------------
// corr_mfma: per (k,b) block, 192x192x128 GEMM = bf16(f) * (m_hi + m_lo).
// 6 waves (2x3), wave tile 96x64. A: global->reg double-buffered.
// B: global_load_lds double-buffered (12 KB/step). Epilogue: dual max-pool
// via registers + transposed LDS scatter (2 wy-passes), then fc_w dot.
// ---------------------------------------------------------------------------
__global__ __launch_bounds__(384, 3) void corr_mfma(
    const __bf16* __restrict__ A2,
    const __bf16* __restrict__ B2,
    const float* __restrict__ fc_w,
    float* __restrict__ dot_sw,
    float* __restrict__ psum,
    float* __restrict__ psq)
{
    __shared__ __align__(16) char smem[40320];
    // staging view: [2][12 tiles][64][8]  (tiles 0-5 = B hi, 6-11 = B lo)
    __bf16 (*lds)[12][64][8] = (__bf16 (*)[12][64][8])smem;

    const int tid = threadIdx.x;
    const int l   = tid & 63;
    const int w   = tid >> 6;     // 0..5
    const int wy  = w / 3;        // M half (96 rows each)
    const int wx  = w % 3;        // N third (64 cols each)
    const int hi  = l >> 5;

    const int bid = blockIdx.x;
    const int kb  = (bid & 7) * 512 + (bid >> 3);   // XCD-contiguous k ranges
    const int k   = kb >> 5;
    const int b   = kb & 31;

    f32x16 acc[3][2];
#pragma unroll
    for (int i = 0; i < 3; ++i)
#pragma unroll
        for (int j = 0; j < 2; ++j)
#pragma unroll
            for (int rr = 0; rr < 16; ++rr) acc[i][j][rr] = 0.f;

    // A: this wave's 3 row-tiles, direct to regs. aw + g*3072 + i*512
    const __bf16* aw = A2 + (size_t)b * 24576 + wy * 1536 + l * 8;
    // B staging: wave w stages lds tiles 2w, 2w+1
    const __bf16* bsrc = B2 + (size_t)k * 49152 +
                         (w < 3 ? w * 1024 : 24576 + (w - 3) * 1024);

    auto loadA = [&](bf16x8* dst, int g) {
        const __bf16* ap = aw + (size_t)g * 3072;
        dst[0] = *(const bf16x8*)(ap);
        dst[1] = *(const bf16x8*)(ap + 512);
        dst[2] = *(const bf16x8*)(ap + 1024);
    };
    auto stageB = [&](int buf2, int g) {
        const char* src = (const char*)(bsrc + (size_t)g * 3072) + l * 16;
        __builtin_amdgcn_global_load_lds(
            (const __attribute__((address_space(1))) void*)src,
            (__attribute__((address_space(3))) void*)&lds[buf2][2 * w][0][0],
            16, 0, 0);
        __builtin_amdgcn_global_load_lds(
            (const __attribute__((address_space(1))) void*)(src + 1024),
            (__attribute__((address_space(3))) void*)&lds[buf2][2 * w + 1][0][0],
            16, 0, 0);
    };
    auto compute = [&](int buf2, bf16x8* a) {
        bf16x8 bh0 = *(const bf16x8*)&lds[buf2][wx * 2][l][0];
        bf16x8 bh1 = *(const bf16x8*)&lds[buf2][wx * 2 + 1][l][0];
        bf16x8 bl0 = *(const bf16x8*)&lds[buf2][6 + wx * 2][l][0];
        bf16x8 bl1 = *(const bf16x8*)&lds[buf2][6 + wx * 2 + 1][l][0];
#pragma unroll
        for (int i = 0; i < 3; ++i) {
            acc[i][0] = __builtin_amdgcn_mfma_f32_32x32x16_bf16(a[i], bh0, acc[i][0], 0, 0, 0);
            acc[i][0] = __builtin_amdgcn_mfma_f32_32x32x16_bf16(a[i], bl0, acc[i][0], 0, 0, 0);
            acc[i][1] = __builtin_amdgcn_mfma_f32_32x32x16_bf16(a[i], bh1, acc[i][1], 0, 0, 0);
            acc[i][1] = __builtin_amdgcn_mfma_f32_32x32x16_bf16(a[i], bl1, acc[i][1], 0, 0, 0);
        }
    };

    bf16x8 aA[3], aB[3];
    loadA(aA, 0);
    stageB(0, 0);
    __syncthreads();
#pragma unroll
    for (int g = 0; g < 8; ++g) {
        bf16x8* acur = (g & 1) ? aB : aA;
        bf16x8* anxt = (g & 1) ? aA : aB;
        if (g < 7) {
            stageB((g & 1) ^ 1, g + 1);
            loadA(anxt, g + 1);
        }
        compute(g & 1, acur);
        __syncthreads();
    }

    // ---- dual-axis max pool ----
    // C/D layout: col = l&31, row = (rr&3) + 8*(rr>>2) + 4*hi  (verified R2)
    float cm[2];
#pragma unroll
    for (int j = 0; j < 2; ++j) {
        float m = -INFINITY;
#pragma unroll
        for (int i = 0; i < 3; ++i)
#pragma unroll
            for (int rr = 0; rr < 16; ++rr) m = fmaxf(m, acc[i][j][rr]);
        cm[j] = m;
    }
#pragma unroll
    for (int j = 0; j < 2; ++j) cm[j] = fmaxf(cm[j], __shfl_xor(cm[j], 32));

    float rm[3][16];
#pragma unroll
    for (int i = 0; i < 3; ++i)
#pragma unroll
        for (int rr = 0; rr < 16; ++rr)
            rm[i][rr] = fmaxf(acc[i][0][rr], acc[i][1][rr]);

    float* rowpart = (float*)smem;           // [96][97] padded
    float* scores  = (float*)smem + 9312;    // [384]
    float* colred  = (float*)smem + 9696;    // [2][192]

    if (l < 32) {
#pragma unroll
        for (int j = 0; j < 2; ++j)
            colred[wy * 192 + wx * 64 + j * 32 + l] = cm[j];
    }
    if (wy == 0) {
#pragma unroll
        for (int i = 0; i < 3; ++i)
#pragma unroll
            for (int rr = 0; rr < 16; ++rr) {
                int q = i * 32 + (rr & 3) + 8 * (rr >> 2) + 4 * hi;
                rowpart[q * 97 + wx * 32 + (l & 31)] = rm[i][rr];
            }
    }
    __syncthreads();
    // colmax combine + rowmax reduce pass A (q in [0,96))
    if (tid < 192) scores[tid] = fmaxf(colred[tid], colred[192 + tid]);
    {
        int q = tid >> 2, part = tid & 3;
        float v = -INFINITY;
#pragma unroll
        for (int c = 0; c < 24; ++c) v = fmaxf(v, rowpart[q * 97 + part * 24 + c]);
        v = fmaxf(v, __shfl_xor(v, 1));
        v = fmaxf(v, __shfl_xor(v, 2));
        if (part == 0) scores[192 + q] = v;
    }
    __syncthreads();
    if (wy == 1) {
#pragma unroll
        for (int i = 0; i < 3; ++i)
#pragma unroll
            for (int rr = 0; rr < 16; ++rr) {
                int q = i * 32 + (rr & 3) + 8 * (rr >> 2) + 4 * hi;
                rowpart[q * 97 + wx * 32 + (l & 31)] = rm[i][rr];
            }
    }
    __syncthreads();
    {
        int q = tid >> 2, part = tid & 3;
        float v = -INFINITY;
#pragma unroll
        for (int c = 0; c < 24; ++c) v = fmaxf(v, rowpart[q * 97 + part * 24 + c]);
        v = fmaxf(v, __shfl_xor(v, 1));
        v = fmaxf(v, __shfl_xor(v, 2));
        if (part == 0) scores[192 + 96 + q] = v;
    }
    __syncthreads();

    // ---- dot with fc_w + BN partial sums over the 384 scores ----
    if (tid < 64) {
        float ds = 0.f, s1 = 0.f, s2 = 0.f;
#pragma unroll
        for (int u = 0; u < 6; ++u) {
            int j = tid + 64 * u;
            float s = scores[j];
            float ww = fc_w[j];
            ds = fmaf(s, ww, ds);
            s1 += s;
            s2 = fmaf(s, s, s2);
        }
        for (int off = 32; off > 0; off >>= 1) {
            ds += __shfl_down(ds, off);
            s1 += __shfl_down(s1, off);
            s2 += __shfl_down(s2, off);
        }
        if (tid == 0) { dot_sw[kb] = ds; psum[kb] = s1; psq[kb] = s2; }
    }
}

// ---------------------------------------------------------------------------
// finalize: BN1 -> folded FC -> BN2 -> focal BCE + argmax (unchanged)
// ---------------------------------------------------------------------------
__device__ __forceinline__ float softplusf(float x) {
    return fmaxf(x, 0.f) + log1pf(expf(-fabsf(x)));
}

__device__ __forceinline__ float block_sum1024(float v, float* tmp) {
    __syncthreads();
    for (int off = 32; off > 0; off >>= 1) v += __shfl_down(v, off);
    if ((threadIdx.x & 63) == 0) tmp[threadIdx.x >> 6] = v;
    __syncthreads();
    float r = 0.f;
#pragma unroll
    for (int i = 0; i < 16; ++i) r += tmp[i];
    return r;
}

__global__ __launch_bounds__(1024) void finalize_kernel(
    const float* __restrict__ dot_sw,
    const float* __restrict__ psum,
    const float* __restrict__ psq,
    const float* __restrict__ fc_w,
    const float* __restrict__ fc_b,
    const float* __restrict__ bn_gamma,
    const float* __restrict__ bn_beta,
    const float* __restrict__ logit_gamma,
    const float* __restrict__ logit_beta,
    const int* __restrict__ target,
    float* __restrict__ out)
{
    const int tid = threadIdx.x;
    __shared__ float l_s[NKB];
    __shared__ float tmp[16];

    float s1 = 0.f, s2 = 0.f, sw = 0.f;
#pragma unroll
    for (int u = 0; u < 4; ++u) {
        int i = tid + 1024 * u;
        s1 += psum[i];
        s2 += psq[i];
    }
    if (tid < P2) sw = fc_w[tid];

    float S1 = block_sum1024(s1, tmp);
    float S2 = block_sum1024(s2, tmp);
    float SW = block_sum1024(sw, tmp);

    const float N1 = (float)NKB * (float)P2;
    float mean1 = S1 / N1;
    float var1  = S2 / N1 - mean1 * mean1;
    float cA = bn_gamma[0] * rsqrtf(var1 + 1e-5f);
    float cB = (bn_beta[0] - cA * mean1) * SW + fc_b[0];

    float lr[4];
    float t1 = 0.f, t2 = 0.f;
#pragma unroll
    for (int u = 0; u < 4; ++u) {
        int i = tid + 1024 * u;
        lr[u] = fmaf(cA, dot_sw[i], cB);
        t1 += lr[u];
        t2 = fmaf(lr[u], lr[u], t2);
    }
    float T1 = block_sum1024(t1, tmp);
    float T2 = block_sum1024(t2, tmp);
    float mean2 = T1 / (float)NKB;
    float var2  = T2 / (float)NKB - mean2 * mean2;
    float cC = logit_gamma[0] * rsqrtf(var2 + 1e-5f);
    float cD = logit_beta[0] - mean2 * cC;

#pragma unroll
    for (int u = 0; u < 4; ++u) {
        int i = tid + 1024 * u;
        l_s[i] = fmaf(lr[u], cC, cD);
    }
    __syncthreads();

    const int b  = tid >> 5;
    const int tt = tid & 31;
    const int tgt = target[b];
    float loss  = 0.f;
    float bestv = -INFINITY;
    int   bestk = 0x7fffffff;
#pragma unroll
    for (int u = 0; u < 4; ++u) {
        int kk = tt + 32 * u;
        float lg = l_s[kk * BB + b];
        float prob = 1.f / (1.f + expf(-lg));
        bool pos = (kk == tgt);
        float wgt = pos ? (1.f - prob) : prob;
        float bce = pos ? softplusf(-lg) : softplusf(lg);
        loss += bce * wgt * wgt;
        if (lg > bestv) { bestv = lg; bestk = kk; }
        else if (lg == bestv && kk < bestk) bestk = kk;
    }
    for (int off = 16; off > 0; off >>= 1) {
        loss += __shfl_down(loss, off, 32);
        float ov = __shfl_down(bestv, off, 32);
        int   ok = __shfl_down(bestk, off, 32);
        if (ov > bestv) { bestv = ov; bestk = ok; }
        else if (ov == bestv && ok < bestk) bestk = ok;
    }
    if (tt == 0) {
        out[b]      = loss;
        out[BB + b] = (bestk == tgt) ? 1.f : 0.f;
    }
}

extern "C" void kernel_launch(void* const* d_in, const int* in_sizes, int n_in,
                              void* d_out, int out_size, void* d_ws, size_t ws_size,
                              hipStream_t stream)
{
    const float* feature      = (const float*)d_in[0];
    const int*   target       = (const int*)d_in[1];
    const float* class_memory = (const float*)d_in[2];
    const float* bn_gamma     = (const float*)d_in[3];
    const float* bn_beta      = (const float*)d_in[4];
    const float* fc_w         = (const float*)d_in[5];
    const float* fc_b         = (const float*)d_in[6];
    const float* logit_gamma  = (const float*)d_in[7];
    const float* logit_beta   = (const float*)d_in[8];
    float* out = (float*)d_out;

    __bf16* A2 = (__bf16*)d_ws;
    __bf16* B2 = A2 + A_ELEMS;
    float* dot_sw = (float*)(B2 + B_ELEMS);
    float* psum   = dot_sw + NKB;
    float* psq    = psum + NKB;

    pack_kernel<<<1920, 256, 0, stream>>>(feature, class_memory, A2, B2);
    corr_mfma<<<NKB, 384, 0, stream>>>(A2, B2, fc_w, dot_sw, psum, psq);
    finalize_kernel<<<1, 1024, 0, stream>>>(dot_sw, psum, psq, fc_w, fc_b,
                                            bn_gamma, bn_beta,
                                            logit_gamma, logit_beta,
                                            target, out);
}

// Round 4
// 198.826 us; speedup vs baseline: 2.4808x; 1.0285x over previous
//
#include <hip/hip_runtime.h>
#include <math.h>

#define BB 32
#define CCH 128
#define KK 128
#define HWW 192
#define NKB (KK * BB)   // 4096
#define P2 (2 * HWW)    // 384

typedef __attribute__((ext_vector_type(8))) __bf16 bf16x8;
typedef __attribute__((ext_vector_type(16))) float f32x16;

// A pack: feature, hi only:  [b][ks 0..7][tile 0..5][lane][8]   (48KB per b)
// B pack: memory, hi+lo:     [k][ks2 0..15][tile 0..5][lane][8] (8..15 = lo)
#define A_ELEMS (BB * 8 * 6 * 512)    // 786,432
#define B_ELEMS (KK * 16 * 6 * 512)   // 6,291,456

// ---------------------------------------------------------------------------
// pack: fp32 [ent][c][hw] -> bf16 MFMA-fragment packs (layout verified R2/R3).
// ---------------------------------------------------------------------------
__global__ __launch_bounds__(256) void pack_kernel(
    const float* __restrict__ feature,
    const float* __restrict__ class_memory,
    __bf16* __restrict__ A2,
    __bf16* __restrict__ B2)
{
    int gid = blockIdx.x * 256 + threadIdx.x;   // 1920*256 = 491,520
    if (gid < 98304) {                          // A: 32*8*6*64
        int l = gid & 63;
        int r = gid >> 6;
        int t = r % 6;  r /= 6;
        int ks = r & 7;
        int e = r >> 3;
        const float* src = feature + (size_t)e * CCH * HWW;
        int c0 = ks * 16 + (l >> 5) * 8;
        int q  = t * 32 + (l & 31);
        bf16x8 v;
#pragma unroll
        for (int j = 0; j < 8; ++j) v[j] = (__bf16)src[(c0 + j) * HWW + q];
        *(bf16x8*)(A2 + ((size_t)(e * 8 + ks) * 6 + t) * 512 + l * 8) = v;
    } else {                                    // B: 128*8*6*64 (hi+lo fused)
        int g2 = gid - 98304;
        int l = g2 & 63;
        int r = g2 >> 6;
        int t = r % 6;  r /= 6;
        int ks = r & 7;
        int e = r >> 3;
        const float* src = class_memory + (size_t)e * CCH * HWW;
        int c0 = ks * 16 + (l >> 5) * 8;
        int q  = t * 32 + (l & 31);
        bf16x8 vh, vl;
#pragma unroll
        for (int j = 0; j < 8; ++j) {
            float x = src[(c0 + j) * HWW + q];
            __bf16 h = (__bf16)x;
            vh[j] = h;
            vl[j] = (__bf16)(x - (float)h);
        }
        __bf16* base = B2 + ((size_t)e * 16 + ks) * 3072 + t * 512 + l * 8;
        *(bf16x8*)base = vh;
        *(bf16x8*)(base + 8 * 3072) = vl;       // lo at ks2 = 8+ks
    }
}

// ---------------------------------------------------------------------------
// corr_mfma: block = (k, half of b's). 12 waves (2 wy x 6 wx), wave tile
// 96x32. B-hi in regs (whole block), B-lo in LDS (whole block), A[b] staged
// per b. Dual-orientation MFMA: acc = corr tile (colmax lane-local),
// acc2 = corr^T tile (rowmax lane-local) -> no cross-lane max reductions.
// ---------------------------------------------------------------------------
#define MFMA32(A, B, C) __builtin_amdgcn_mfma_f32_32x32x16_bf16((A), (B), (C), 0, 0, 0)

__global__ __launch_bounds__(768, 3) void corr_mfma(
    const __bf16* __restrict__ A2,
    const __bf16* __restrict__ B2,
    const float* __restrict__ fc_w,
    float* __restrict__ dot_sw,
    float* __restrict__ psum,
    float* __restrict__ psq)
{
    __shared__ __align__(16) __bf16 A_lds[8][6][64][8];    // 48 KB, restaged per b
    __shared__ __align__(16) __bf16 Blo_lds[8][6][64][8];  // 48 KB, loaded once
    __shared__ float colpart[2][192];
    __shared__ float rowpart[6][192];
    __shared__ float scores[384];

    const int tid = threadIdx.x;
    const int l   = tid & 63;
    const int lc  = l & 31;
    const int w   = tid >> 6;      // 0..11
    const int wy  = w / 6;         // 0..1 : 96-row half
    const int wx  = w % 6;         // 0..5 : 32-col tile

    // XCD-contiguous k ranges: each XCD's L2 caches a 16-k slice of B2.
    const int bid   = blockIdx.x;
    const int xcd   = bid & 7;
    const int slot  = bid >> 3;            // 0..31
    const int k     = xcd * 16 + (slot >> 1);
    const int bhalf = slot & 1;

    // ---- B-hi fragments for this wave's coltile: held in regs all block ----
    const __bf16* bkbase = B2 + (size_t)k * 49152;
    bf16x8 bh[8];
#pragma unroll
    for (int g = 0; g < 8; ++g)
        bh[g] = *(const bf16x8*)(bkbase + g * 3072 + wx * 512 + l * 8);

    float fcw[6];
#pragma unroll
    for (int u = 0; u < 6; ++u) fcw[u] = fc_w[l + 64 * u];

    // ---- stage B-lo (once) and A[b0] ----
    const char* lobase = (const char*)B2 + (size_t)k * 98304 + 49152;
    const char* abase  = (const char*)A2;
    char* lodst = (char*)&Blo_lds[0][0][0][0];
    char* adst  = (char*)&A_lds[0][0][0][0];
    const int woff = w * 1024 + l * 16;    // per-lane src offset
    const int wbase = w * 1024;            // wave-uniform LDS offset

    auto stageA = [&](int b) {
        const char* src = abase + (size_t)b * 49152;
#pragma unroll
        for (int i = 0; i < 4; ++i)
            __builtin_amdgcn_global_load_lds(
                (const __attribute__((address_space(1))) void*)(src + i * 12288 + woff),
                (__attribute__((address_space(3))) void*)(adst + i * 12288 + wbase),
                16, 0, 0);
    };
#pragma unroll
    for (int i = 0; i < 4; ++i)
        __builtin_amdgcn_global_load_lds(
            (const __attribute__((address_space(1))) void*)(lobase + i * 12288 + woff),
            (__attribute__((address_space(3))) void*)(lodst + i * 12288 + wbase),
            16, 0, 0);
    stageA(bhalf * 16);
    __syncthreads();

    for (int bi = 0; bi < 16; ++bi) {
        const int b = bhalf * 16 + bi;

        f32x16 acc[3], acc2[3];
#pragma unroll
        for (int i = 0; i < 3; ++i)
#pragma unroll
            for (int rr = 0; rr < 16; ++rr) { acc[i][rr] = 0.f; acc2[i][rr] = 0.f; }

#pragma unroll
        for (int g = 0; g < 8; ++g) {
            bf16x8 a0 = *(const bf16x8*)&A_lds[g][wy * 3 + 0][l][0];
            bf16x8 a1 = *(const bf16x8*)&A_lds[g][wy * 3 + 1][l][0];
            bf16x8 a2 = *(const bf16x8*)&A_lds[g][wy * 3 + 2][l][0];
            bf16x8 bl = *(const bf16x8*)&Blo_lds[g][wx][l][0];
            acc[0]  = MFMA32(a0, bh[g], acc[0]);
            acc[0]  = MFMA32(a0, bl,    acc[0]);
            acc[1]  = MFMA32(a1, bh[g], acc[1]);
            acc[1]  = MFMA32(a1, bl,    acc[1]);
            acc[2]  = MFMA32(a2, bh[g], acc[2]);
            acc[2]  = MFMA32(a2, bl,    acc[2]);
            acc2[0] = MFMA32(bh[g], a0, acc2[0]);
            acc2[0] = MFMA32(bl,    a0, acc2[0]);
            acc2[1] = MFMA32(bh[g], a1, acc2[1]);
            acc2[1] = MFMA32(bl,    a1, acc2[1]);
            acc2[2] = MFMA32(bh[g], a2, acc2[2]);
            acc2[2] = MFMA32(bl,    a2, acc2[2]);
        }

        // ---- epilogue: both maxes are lane-local scans now ----
        // acc[i]:  rows q = wy*96 + i*32 + rowfn(rr,hi), col p = wx*32 + lc
        // acc2[i]: rows p = wx*32 + rowfn(rr,hi), col q = (wy*3+i)*32 + lc
        float cmv = -INFINITY;
#pragma unroll
        for (int i = 0; i < 3; ++i)
#pragma unroll
            for (int rr = 0; rr < 16; ++rr) cmv = fmaxf(cmv, acc[i][rr]);
        cmv = fmaxf(cmv, __shfl_xor(cmv, 32));
        if (l < 32) colpart[wy][wx * 32 + lc] = cmv;   // max over wy-half rows, per p

#pragma unroll
        for (int i = 0; i < 3; ++i) {
            float t = -INFINITY;
#pragma unroll
            for (int rr = 0; rr < 16; ++rr) t = fmaxf(t, acc2[i][rr]);
            t = fmaxf(t, __shfl_xor(t, 32));
            if (l < 32) rowpart[wx][(wy * 3 + i) * 32 + lc] = t;  // max over coltile p, per q
        }
        __syncthreads();                 // A reads done + partials visible

        if (bi < 15) stageA(b + 1);      // overlap restage with reduce/dot

        if (tid < 192) {
            scores[tid] = fmaxf(colpart[0][tid], colpart[1][tid]);
        } else if (tid < 384) {
            int q = tid - 192;
            float v = rowpart[0][q];
#pragma unroll
            for (int x = 1; x < 6; ++x) v = fmaxf(v, rowpart[x][q]);
            scores[192 + q] = v;
        }
        __syncthreads();                 // scores visible; drains A stage

        if (tid < 64) {
            float ds = 0.f, s1 = 0.f, s2 = 0.f;
#pragma unroll
            for (int u = 0; u < 6; ++u) {
                float s = scores[l + 64 * u];
                ds = fmaf(s, fcw[u], ds);
                s1 += s;
                s2 = fmaf(s, s, s2);
            }
            for (int off = 32; off > 0; off >>= 1) {
                ds += __shfl_down(ds, off);
                s1 += __shfl_down(s1, off);
                s2 += __shfl_down(s2, off);
            }
            if (tid == 0) {
                int kb = k * 32 + b;
                dot_sw[kb] = ds;
                psum[kb]   = s1;
                psq[kb]    = s2;
            }
        }
    }
}

// ---------------------------------------------------------------------------
// finalize: BN1 -> folded FC -> BN2 -> focal BCE + argmax (unchanged)
// ---------------------------------------------------------------------------
__device__ __forceinline__ float softplusf(float x) {
    return fmaxf(x, 0.f) + log1pf(expf(-fabsf(x)));
}

__device__ __forceinline__ float block_sum1024(float v, float* tmp) {
    __syncthreads();
    for (int off = 32; off > 0; off >>= 1) v += __shfl_down(v, off);
    if ((threadIdx.x & 63) == 0) tmp[threadIdx.x >> 6] = v;
    __syncthreads();
    float r = 0.f;
#pragma unroll
    for (int i = 0; i < 16; ++i) r += tmp[i];
    return r;
}

__global__ __launch_bounds__(1024) void finalize_kernel(
    const float* __restrict__ dot_sw,
    const float* __restrict__ psum,
    const float* __restrict__ psq,
    const float* __restrict__ fc_w,
    const float* __restrict__ fc_b,
    const float* __restrict__ bn_gamma,
    const float* __restrict__ bn_beta,
    const float* __restrict__ logit_gamma,
    const float* __restrict__ logit_beta,
    const int* __restrict__ target,
    float* __restrict__ out)
{
    const int tid = threadIdx.x;
    __shared__ float l_s[NKB];
    __shared__ float tmp[16];

    float s1 = 0.f, s2 = 0.f, sw = 0.f;
#pragma unroll
    for (int u = 0; u < 4; ++u) {
        int i = tid + 1024 * u;
        s1 += psum[i];
        s2 += psq[i];
    }
    if (tid < P2) sw = fc_w[tid];

    float S1 = block_sum1024(s1, tmp);
    float S2 = block_sum1024(s2, tmp);
    float SW = block_sum1024(sw, tmp);

    const float N1 = (float)NKB * (float)P2;
    float mean1 = S1 / N1;
    float var1  = S2 / N1 - mean1 * mean1;
    float cA = bn_gamma[0] * rsqrtf(var1 + 1e-5f);
    float cB = (bn_beta[0] - cA * mean1) * SW + fc_b[0];

    float lr[4];
    float t1 = 0.f, t2 = 0.f;
#pragma unroll
    for (int u = 0; u < 4; ++u) {
        int i = tid + 1024 * u;
        lr[u] = fmaf(cA, dot_sw[i], cB);
        t1 += lr[u];
        t2 = fmaf(lr[u], lr[u], t2);
    }
    float T1 = block_sum1024(t1, tmp);
    float T2 = block_sum1024(t2, tmp);
    float mean2 = T1 / (float)NKB;
    float var2  = T2 / (float)NKB - mean2 * mean2;
    float cC = logit_gamma[0] * rsqrtf(var2 + 1e-5f);
    float cD = logit_beta[0] - mean2 * cC;

#pragma unroll
    for (int u = 0; u < 4; ++u) {
        int i = tid + 1024 * u;
        l_s[i] = fmaf(lr[u], cC, cD);
    }
    __syncthreads();

    const int b  = tid >> 5;
    const int tt = tid & 31;
    const int tgt = target[b];
    float loss  = 0.f;
    float bestv = -INFINITY;
    int   bestk = 0x7fffffff;
#pragma unroll
    for (int u = 0; u < 4; ++u) {
        int kk = tt + 32 * u;
        float lg = l_s[kk * BB + b];
        float prob = 1.f / (1.f + expf(-lg));
        bool pos = (kk == tgt);
        float wgt = pos ? (1.f - prob) : prob;
        float bce = pos ? softplusf(-lg) : softplusf(lg);
        loss += bce * wgt * wgt;
        if (lg > bestv) { bestv = lg; bestk = kk; }
        else if (lg == bestv && kk < bestk) bestk = kk;
    }
    for (int off = 16; off > 0; off >>= 1) {
        loss += __shfl_down(loss, off, 32);
        float ov = __shfl_down(bestv, off, 32);
        int   ok = __shfl_down(bestk, off, 32);
        if (ov > bestv) { bestv = ov; bestk = ok; }
        else if (ov == bestv && ok < bestk) bestk = ok;
    }
    if (tt == 0) {
        out[b]      = loss;
        out[BB + b] = (bestk == tgt) ? 1.f : 0.f;
    }
}

extern "C" void kernel_launch(void* const* d_in, const int* in_sizes, int n_in,
                              void* d_out, int out_size, void* d_ws, size_t ws_size,
                              hipStream_t stream)
{
    const float* feature      = (const float*)d_in[0];
    const int*   target       = (const int*)d_in[1];
    const float* class_memory = (const float*)d_in[2];
    const float* bn_gamma     = (const float*)d_in[3];
    const float* bn_beta      = (const float*)d_in[4];
    const float* fc_w         = (const float*)d_in[5];
    const float* fc_b         = (const float*)d_in[6];
    const float* logit_gamma  = (const float*)d_in[7];
    const float* logit_beta   = (const float*)d_in[8];
    float* out = (float*)d_out;

    __bf16* A2 = (__bf16*)d_ws;
    __bf16* B2 = A2 + A_ELEMS;
    float* dot_sw = (float*)(B2 + B_ELEMS);
    float* psum   = dot_sw + NKB;
    float* psq    = psum + NKB;

    pack_kernel<<<1920, 256, 0, stream>>>(feature, class_memory, A2, B2);
    corr_mfma<<<256, 768, 0, stream>>>(A2, B2, fc_w, dot_sw, psum, psq);
    finalize_kernel<<<1, 1024, 0, stream>>>(dot_sw, psum, psq, fc_w, fc_b,
                                            bn_gamma, bn_beta,
                                            logit_gamma, logit_beta,
                                            target, out);
}